// Round 2
// baseline (209.732 us; speedup 1.0000x reference)
//
#include <hip/hip_runtime.h>
#include <hip/hip_bf16.h>
#include <cstdint>

#define TSEQ 4096
#define NB   4
#define HD   64
#define CEMB 1024

typedef __attribute__((ext_vector_type(8))) short bfrag;   // 8 bf16 = 4 VGPRs
typedef __attribute__((ext_vector_type(4))) float f4;

#define MFMA16(a, b, c) __builtin_amdgcn_mfma_f32_16x16x32_bf16(a, b, c, 0, 0, 0)

static __device__ __forceinline__ unsigned short f2bf(float f) {
    __hip_bfloat16 h = __float2bfloat16(f);
    return __builtin_bit_cast(unsigned short, h);
}

static __device__ __forceinline__ bfrag cvt8(const float* p) {
    const float4 a = *reinterpret_cast<const float4*>(p);
    const float4 b = *reinterpret_cast<const float4*>(p + 4);
    bfrag r;
    r[0] = (short)f2bf(a.x); r[1] = (short)f2bf(a.y);
    r[2] = (short)f2bf(a.z); r[3] = (short)f2bf(a.w);
    r[4] = (short)f2bf(b.x); r[5] = (short)f2bf(b.y);
    r[6] = (short)f2bf(b.z); r[7] = (short)f2bf(b.w);
    return r;
}

// ---------------------------------------------------------------------------
// Projection: q = x Wq^T, k = x Wk^T, v = x Wv^T  -> bf16, v stored transposed
// Each wave: 32 rows (2 MFMA row-tiles) x 192 cols (12 col-tiles).
// Block: 4 waves = 128 rows. Grid: 16384/128 = 128 blocks.
// ---------------------------------------------------------------------------
__global__ __launch_bounds__(256) void proj_kernel(
    const float* __restrict__ x,  const float* __restrict__ Wq,
    const float* __restrict__ Wk, const float* __restrict__ Wv,
    unsigned short* __restrict__ qb, unsigned short* __restrict__ kb,
    unsigned short* __restrict__ vt)
{
    const int w    = threadIdx.x >> 6;
    const int lane = threadIdx.x & 63;
    const int ln15 = lane & 15, lg = lane >> 4;
    const int row0 = blockIdx.x * 128 + w * 32;

    f4 acc[2][12];
    #pragma unroll
    for (int i = 0; i < 2; ++i)
        #pragma unroll
        for (int j = 0; j < 12; ++j) acc[i][j] = f4{0.f, 0.f, 0.f, 0.f};

    for (int k0 = 0; k0 < CEMB; k0 += 32) {
        bfrag a[2];
        #pragma unroll
        for (int rt = 0; rt < 2; ++rt)
            a[rt] = cvt8(x + (size_t)(row0 + rt * 16 + ln15) * CEMB + k0 + 8 * lg);
        #pragma unroll
        for (int ct = 0; ct < 12; ++ct) {
            const float* W = (ct < 4) ? Wq : (ct < 8) ? Wk : Wv;
            const int h = (ct & 3) * 16 + ln15;
            bfrag bw = cvt8(W + (size_t)h * CEMB + k0 + 8 * lg);
            acc[0][ct] = MFMA16(a[0], bw, acc[0][ct]);
            acc[1][ct] = MFMA16(a[1], bw, acc[1][ct]);
        }
    }

    // D layout: col = lane&15, row = 4*(lane>>4) + reg   [m89-verified]
    #pragma unroll
    for (int rt = 0; rt < 2; ++rt) {
        #pragma unroll
        for (int ct = 0; ct < 12; ++ct) {
            #pragma unroll
            for (int r = 0; r < 4; ++r) {
                const int grow = row0 + rt * 16 + 4 * lg + r;
                const unsigned short bv = f2bf(acc[rt][ct][r]);
                const int h = (ct & 3) * 16 + ln15;
                if (ct < 4)       qb[(size_t)grow * HD + h] = bv;
                else if (ct < 8)  kb[(size_t)grow * HD + h] = bv;
                else {
                    const int bbi = grow >> 12, t = grow & 4095;
                    vt[((size_t)(bbi * HD + h) << 12) + t] = bv;  // vt[b][h][t]
                }
            }
        }
    }
}

// ---------------------------------------------------------------------------
// Flash attention. Block = 8 waves (512 thr): waves 0-3 = KV half 0,
// waves 4-7 = KV half 1; qsub = w&3 picks one of four 16-row q-slices.
// Grid: 16384/64 = 256 blocks. K/V tiles staged in XOR-swizzled LDS,
// P transposed through wave-private swizzled LDS, halves merged via LDS.
// ---------------------------------------------------------------------------
#define SCL 0.18033688011112042f  // 0.125 * log2(e)

__global__ __launch_bounds__(512) void attn_kernel(
    const unsigned short* __restrict__ qb, const unsigned short* __restrict__ kb,
    const unsigned short* __restrict__ vt, float* __restrict__ out)
{
    __shared__ __attribute__((aligned(16))) unsigned short kbuf[2][64 * 64];
    __shared__ __attribute__((aligned(16))) unsigned short vbuf[2][64 * 64];
    __shared__ __attribute__((aligned(16))) unsigned short pbuf[8][16 * 64];
    __shared__ float mo[4][16][64];
    __shared__ float mm[4][16], ml[4][16];

    const int w    = threadIdx.x >> 6;
    const int lane = threadIdx.x & 63;
    const int ln15 = lane & 15, lg = lane >> 4;
    const int qsub = w & 3, half = w >> 2;
    const int qrow0 = blockIdx.x * 64 + qsub * 16;   // global q row base
    const int bb    = (blockIdx.x * 64) >> 12;       // batch index

    // Q fragments (A-operand): row = ln15, k(d) = dc*32 + 8*lg + j
    bfrag aq[2];
    #pragma unroll
    for (int dc = 0; dc < 2; ++dc)
        aq[dc] = *reinterpret_cast<const bfrag*>(
            qb + (size_t)(qrow0 + ln15) * HD + dc * 32 + 8 * lg);

    f4 o[4];
    float m[4], l[4];
    #pragma unroll
    for (int i = 0; i < 4; ++i) {
        o[i] = f4{0.f, 0.f, 0.f, 0.f};
        m[i] = -__builtin_inff();
        l[i] = 0.f;
    }

    char* kbh = (char*)&kbuf[half][0];
    char* vbh = (char*)&vbuf[half][0];
    char* pb  = (char*)&pbuf[w][0];

    const int slot = qsub * 64 + lane;         // 0..255 within half
    const size_t kgbase = (size_t)bb * TSEQ * HD;   // batch offset in kb (elems)
    const size_t vgbase = (size_t)bb * HD * TSEQ;   // batch offset in vt (elems)

    for (int it = 0; it < 32; ++it) {
        const int kv0 = half * 2048 + it * 64;
        __syncthreads();   // previous iteration's reads done before overwrite
        // Stage K tile [64 kv x 64 d] and V tile [64 d x 64 kv]:
        // 512 16B-segments each, 256 threads -> 2 segments per thread.
        #pragma unroll
        for (int s = slot; s < 512; s += 256) {
            const int srow = s >> 3, sseg = s & 7;
            const int dst = srow * 128 + ((sseg * 16) ^ ((srow & 7) << 4));
            bfrag kg = *reinterpret_cast<const bfrag*>(
                kb + kgbase + (size_t)(kv0 + srow) * HD + sseg * 8);
            *reinterpret_cast<bfrag*>(kbh + dst) = kg;
            bfrag vg = *reinterpret_cast<const bfrag*>(
                vt + vgbase + (size_t)srow * TSEQ + kv0 + sseg * 8);
            *reinterpret_cast<bfrag*>(vbh + dst) = vg;
        }
        __syncthreads();   // staging visible

        // S = Q K^T  (4 col-tiles of 16 kj, K-dim 64 = 2 MFMAs each)
        f4 s[4];
        #pragma unroll
        for (int jt = 0; jt < 4; ++jt) {
            const int krow = jt * 16 + ln15;
            const int sw = (krow & 7) << 4;
            bfrag b0 = *reinterpret_cast<const bfrag*>(kbh + krow * 128 + ((lg * 16) ^ sw));
            bfrag b1 = *reinterpret_cast<const bfrag*>(kbh + krow * 128 + ((64 + lg * 16) ^ sw));
            f4 a0 = f4{0.f, 0.f, 0.f, 0.f};
            a0 = MFMA16(aq[0], b0, a0);
            a0 = MFMA16(aq[1], b1, a0);
            s[jt] = a0 * SCL;   // base-2 logits
        }

        // online softmax (rows 4*lg+r live in the 16 consecutive lanes of group lg)
        #pragma unroll
        for (int r = 0; r < 4; ++r) {
            float t = fmaxf(fmaxf(s[0][r], s[1][r]), fmaxf(s[2][r], s[3][r]));
            #pragma unroll
            for (int off = 1; off < 16; off <<= 1) t = fmaxf(t, __shfl_xor(t, off));
            const float mn   = fmaxf(m[r], t);
            const float corr = exp2f(m[r] - mn);
            m[r] = mn;
            float p0 = exp2f(s[0][r] - mn);
            float p1 = exp2f(s[1][r] - mn);
            float p2 = exp2f(s[2][r] - mn);
            float p3 = exp2f(s[3][r] - mn);
            s[0][r] = p0; s[1][r] = p1; s[2][r] = p2; s[3][r] = p3;
            float su = (p0 + p1) + (p2 + p3);
            #pragma unroll
            for (int off = 1; off < 16; off <<= 1) su += __shfl_xor(su, off);
            l[r] = l[r] * corr + su;
            #pragma unroll
            for (int dt = 0; dt < 4; ++dt) o[dt][r] *= corr;
        }

        // P -> wave-private LDS (transpose to A-fragment layout), swizzled
        #pragma unroll
        for (int jt = 0; jt < 4; ++jt)
            #pragma unroll
            for (int r = 0; r < 4; ++r) {
                const int prow = 4 * lg + r, pcol = ln15 + 16 * jt;
                *reinterpret_cast<unsigned short*>(
                    pb + prow * 128 + ((pcol * 2) ^ ((prow & 7) << 4))) = f2bf(s[jt][r]);
            }
        bfrag ap0 = *reinterpret_cast<const bfrag*>(
            pb + ln15 * 128 + ((lg * 16) ^ ((ln15 & 7) << 4)));
        bfrag ap1 = *reinterpret_cast<const bfrag*>(
            pb + ln15 * 128 + ((64 + lg * 16) ^ ((ln15 & 7) << 4)));

        // O += P V
        #pragma unroll
        for (int dt = 0; dt < 4; ++dt) {
            const int vrow = dt * 16 + ln15;
            const int sw = (vrow & 7) << 4;
            bfrag v0 = *reinterpret_cast<const bfrag*>(vbh + vrow * 128 + ((lg * 16) ^ sw));
            bfrag v1 = *reinterpret_cast<const bfrag*>(vbh + vrow * 128 + ((64 + lg * 16) ^ sw));
            o[dt] = MFMA16(ap0, v0, o[dt]);
            o[dt] = MFMA16(ap1, v1, o[dt]);
        }
    }

    // merge the two KV halves (same q rows in waves w and w+4)
    if (half == 1) {
        #pragma unroll
        for (int dt = 0; dt < 4; ++dt)
            #pragma unroll
            for (int r = 0; r < 4; ++r)
                mo[qsub][4 * lg + r][dt * 16 + ln15] = o[dt][r];
        if (ln15 == 0) {
            #pragma unroll
            for (int r = 0; r < 4; ++r) {
                mm[qsub][4 * lg + r] = m[r];
                ml[qsub][4 * lg + r] = l[r];
            }
        }
    }
    __syncthreads();
    if (half == 0) {
        #pragma unroll
        for (int r = 0; r < 4; ++r) {
            const int row = 4 * lg + r;
            const float pm = mm[qsub][row], pl = ml[qsub][row];
            const float ms = fmaxf(m[r], pm);
            const float ca  = exp2f(m[r] - ms);
            const float cb2 = exp2f(pm - ms);
            const float inv = 1.0f / (l[r] * ca + pl * cb2);
            #pragma unroll
            for (int dt = 0; dt < 4; ++dt) {
                const float val = (o[dt][r] * ca + mo[qsub][row][dt * 16 + ln15] * cb2) * inv;
                out[(size_t)(qrow0 + row) * HD + dt * 16 + ln15] = val;
            }
        }
    }
}

// ---------------------------------------------------------------------------
extern "C" void kernel_launch(void* const* d_in, const int* in_sizes, int n_in,
                              void* d_out, int out_size, void* d_ws, size_t ws_size,
                              hipStream_t stream) {
    (void)in_sizes; (void)n_in; (void)out_size; (void)ws_size;
    const float* x  = (const float*)d_in[0];
    const float* Wk = (const float*)d_in[1];
    const float* Wq = (const float*)d_in[2];
    const float* Wv = (const float*)d_in[3];

    unsigned short* qb = (unsigned short*)d_ws;                 // [16384][64] bf16
    unsigned short* kb = qb + (size_t)NB * TSEQ * HD;           // [16384][64] bf16
    unsigned short* vt = kb + (size_t)NB * TSEQ * HD;           // [4][64][4096] bf16

    proj_kernel<<<128, 256, 0, stream>>>(x, Wq, Wk, Wv, qb, kb, vt);
    attn_kernel<<<256, 512, 0, stream>>>(qb, kb, vt, (float*)d_out);
}

// Round 3
// 141.753 us; speedup vs baseline: 1.4796x; 1.4796x over previous
//
#include <hip/hip_runtime.h>
#include <hip/hip_bf16.h>
#include <cstdint>

#define TSEQ 4096
#define NB   4
#define HD   64
#define CEMB 1024
#define NQ   4      // KV quarters (attention parallelism)

typedef __attribute__((ext_vector_type(8))) short bfrag;   // 8 bf16 = 4 VGPRs
typedef __attribute__((ext_vector_type(4))) float f4;

#define MFMA16(a, b, c) __builtin_amdgcn_mfma_f32_16x16x32_bf16(a, b, c, 0, 0, 0)

static __device__ __forceinline__ unsigned short f2bf(float f) {
    __hip_bfloat16 h = __float2bfloat16(f);
    return __builtin_bit_cast(unsigned short, h);
}

static __device__ __forceinline__ bfrag cvt8(const float* p) {
    const float4 a = *reinterpret_cast<const float4*>(p);
    const float4 b = *reinterpret_cast<const float4*>(p + 4);
    bfrag r;
    r[0] = (short)f2bf(a.x); r[1] = (short)f2bf(a.y);
    r[2] = (short)f2bf(a.z); r[3] = (short)f2bf(a.w);
    r[4] = (short)f2bf(b.x); r[5] = (short)f2bf(b.y);
    r[6] = (short)f2bf(b.z); r[7] = (short)f2bf(b.w);
    return r;
}

// ---------------------------------------------------------------------------
// W conversion: Wq|Wk|Wv (each [64][1024] f32) -> wb [192][1024] bf16, once.
// ---------------------------------------------------------------------------
__global__ __launch_bounds__(256) void wcvt_kernel(
    const float* __restrict__ Wq, const float* __restrict__ Wk,
    const float* __restrict__ Wv, unsigned short* __restrict__ wb)
{
    const int row = blockIdx.x;          // 0..191
    const int col = threadIdx.x * 4;     // 0..1020
    const float* W = (row < 64) ? Wq + (size_t)row * CEMB
                   : (row < 128) ? Wk + (size_t)(row - 64) * CEMB
                   : Wv + (size_t)(row - 128) * CEMB;
    const float4 v = *reinterpret_cast<const float4*>(W + col);
    ushort4 o;
    o.x = f2bf(v.x); o.y = f2bf(v.y); o.z = f2bf(v.z); o.w = f2bf(v.w);
    *reinterpret_cast<ushort4*>(wb + (size_t)row * CEMB + col) = o;
}

// ---------------------------------------------------------------------------
// Projection: wave = 16 rows x 96 cols (6 col-tiles). Block = 4 waves
// (2 row-groups x 2 col-halves) = 32 rows. Grid 512 -> 2 blocks/CU.
// B-fragments are direct bf16 loads from L2-resident wb.
// ---------------------------------------------------------------------------
__global__ __launch_bounds__(256) void proj_kernel(
    const float* __restrict__ x, const unsigned short* __restrict__ wb,
    unsigned short* __restrict__ qb, unsigned short* __restrict__ kb,
    unsigned short* __restrict__ vt)
{
    const int w    = threadIdx.x >> 6;
    const int lane = threadIdx.x & 63;
    const int ln15 = lane & 15, lg = lane >> 4;
    const int row0  = blockIdx.x * 32 + (w >> 1) * 16;
    const int cbase = (w & 1) * 96;

    f4 acc[6];
    #pragma unroll
    for (int j = 0; j < 6; ++j) acc[j] = f4{0.f, 0.f, 0.f, 0.f};

    const float* xrow = x + (size_t)(row0 + ln15) * CEMB + 8 * lg;
    const unsigned short* wrow = wb + (size_t)(cbase + ln15) * CEMB + 8 * lg;

    #pragma unroll 2
    for (int k0 = 0; k0 < CEMB; k0 += 32) {
        const bfrag a = cvt8(xrow + k0);
        #pragma unroll
        for (int ct = 0; ct < 6; ++ct) {
            const bfrag bw = *reinterpret_cast<const bfrag*>(wrow + ct * 16 * CEMB + k0);
            acc[ct] = MFMA16(a, bw, acc[ct]);
        }
    }

    // D layout: col = lane&15, row = 4*(lane>>4) + reg
    #pragma unroll
    for (int ct = 0; ct < 6; ++ct) {
        const int c = cbase + ct * 16 + ln15;
        #pragma unroll
        for (int r = 0; r < 4; ++r) {
            const int grow = row0 + 4 * lg + r;
            const unsigned short bv = f2bf(acc[ct][r]);
            if (c < 64)        qb[(size_t)grow * HD + c] = bv;
            else if (c < 128)  kb[(size_t)grow * HD + (c - 64)] = bv;
            else {
                const int bbi = grow >> 12, t = grow & 4095;
                vt[((size_t)(bbi * HD + (c - 128)) << 12) + t] = bv;  // vt[b][h][t]
            }
        }
    }
}

// ---------------------------------------------------------------------------
// Flash attention partials. Grid (256, NQ): blockIdx.x = 64-q-row group,
// blockIdx.y = KV quarter (1024 keys, 16 iters of 64). Block = 4 waves,
// wave = 16 q rows. Async-staged (T14) single-buffered LDS K/V tiles,
// XOR-swizzled. Writes unnormalized (o, m, l) partials to workspace.
// ---------------------------------------------------------------------------
#define SCL 0.18033688011112042f  // 0.125 * log2(e)

__global__ __launch_bounds__(256) void attn_kernel(
    const unsigned short* __restrict__ qb, const unsigned short* __restrict__ kb,
    const unsigned short* __restrict__ vt, float* __restrict__ po,
    float* __restrict__ pm, float* __restrict__ pl)
{
    __shared__ __attribute__((aligned(16))) unsigned short kbuf[64 * 64];
    __shared__ __attribute__((aligned(16))) unsigned short vbuf[64 * 64];
    __shared__ __attribute__((aligned(16))) unsigned short pbuf[4][16 * 64];

    const int w    = threadIdx.x >> 6;
    const int lane = threadIdx.x & 63;
    const int ln15 = lane & 15, lg = lane >> 4;
    const int qrow0 = blockIdx.x * 64 + w * 16;
    const int bb    = blockIdx.x >> 6;            // batch index
    const int kvbase = blockIdx.y * 1024;

    const size_t kgbase = (size_t)bb * TSEQ * HD;
    const size_t vgbase = (size_t)bb * HD * TSEQ;

    // Q fragments (A-operand): row = ln15, k(d) = dc*32 + 8*lg + j
    bfrag aq[2];
    #pragma unroll
    for (int dc = 0; dc < 2; ++dc)
        aq[dc] = *reinterpret_cast<const bfrag*>(
            qb + (size_t)(qrow0 + ln15) * HD + dc * 32 + 8 * lg);

    f4 o[4];
    float m[4], l[4];
    #pragma unroll
    for (int i = 0; i < 4; ++i) {
        o[i] = f4{0.f, 0.f, 0.f, 0.f};
        m[i] = -__builtin_inff();
        l[i] = 0.f;
    }

    char* kbh = (char*)kbuf;
    char* vbh = (char*)vbuf;
    char* pb  = (char*)&pbuf[w][0];

    // staging geometry: 256 threads, K tile 512 segs + V tile 512 segs ->
    // each thread owns K rows rr, rr+32 and V rows rr, rr+32 at segment seg.
    const int rr  = threadIdx.x >> 3;   // 0..31
    const int rr2 = rr + 32;
    const int seg = threadIdx.x & 7;
    const int dstA = rr  * 128 + ((seg * 16) ^ ((rr  & 7) << 4));
    const int dstB = rr2 * 128 + ((seg * 16) ^ ((rr2 & 7) << 4));

    bfrag st0, st1, st2, st3;
    auto LOADT = [&](int kv0) {
        st0 = *reinterpret_cast<const bfrag*>(kb + kgbase + (size_t)(kv0 + rr)  * HD + seg * 8);
        st1 = *reinterpret_cast<const bfrag*>(kb + kgbase + (size_t)(kv0 + rr2) * HD + seg * 8);
        st2 = *reinterpret_cast<const bfrag*>(vt + vgbase + (size_t)rr  * TSEQ + kv0 + seg * 8);
        st3 = *reinterpret_cast<const bfrag*>(vt + vgbase + (size_t)rr2 * TSEQ + kv0 + seg * 8);
    };
    auto WRITET = [&]() {
        *reinterpret_cast<bfrag*>(kbh + dstA) = st0;
        *reinterpret_cast<bfrag*>(kbh + dstB) = st1;
        *reinterpret_cast<bfrag*>(vbh + dstA) = st2;
        *reinterpret_cast<bfrag*>(vbh + dstB) = st3;
    };

    LOADT(kvbase);
    WRITET();
    __syncthreads();

    for (int it = 0; it < 16; ++it) {
        // T14: issue next tile's global loads now; they stay in flight
        // across the compute phase and land in LDS after the barrier.
        LOADT(kvbase + ((it + 1) & 15) * 64);

        // S = Q K^T  (4 col-tiles of 16 kj, K-dim 64 = 2 MFMAs each)
        f4 s[4];
        __builtin_amdgcn_s_setprio(1);
        #pragma unroll
        for (int jt = 0; jt < 4; ++jt) {
            const int krow = jt * 16 + ln15;
            const int sw = (krow & 7) << 4;
            const bfrag b0 = *reinterpret_cast<const bfrag*>(kbh + krow * 128 + ((lg * 16) ^ sw));
            const bfrag b1 = *reinterpret_cast<const bfrag*>(kbh + krow * 128 + ((64 + lg * 16) ^ sw));
            f4 a0 = f4{0.f, 0.f, 0.f, 0.f};
            a0 = MFMA16(aq[0], b0, a0);
            a0 = MFMA16(aq[1], b1, a0);
            s[jt] = a0 * SCL;   // base-2 logits
        }
        __builtin_amdgcn_s_setprio(0);

        // online softmax; q-row 4*lg+r lives in the 16 lanes of group lg
        #pragma unroll
        for (int r = 0; r < 4; ++r) {
            float t = fmaxf(fmaxf(s[0][r], s[1][r]), fmaxf(s[2][r], s[3][r]));
            #pragma unroll
            for (int off = 1; off < 16; off <<= 1) t = fmaxf(t, __shfl_xor(t, off));
            const float mn   = fmaxf(m[r], t);
            const float corr = exp2f(m[r] - mn);
            m[r] = mn;
            float p0 = exp2f(s[0][r] - mn);
            float p1 = exp2f(s[1][r] - mn);
            float p2 = exp2f(s[2][r] - mn);
            float p3 = exp2f(s[3][r] - mn);
            s[0][r] = p0; s[1][r] = p1; s[2][r] = p2; s[3][r] = p3;
            float su = (p0 + p1) + (p2 + p3);
            #pragma unroll
            for (int off = 1; off < 16; off <<= 1) su += __shfl_xor(su, off);
            l[r] = l[r] * corr + su;
            #pragma unroll
            for (int dt = 0; dt < 4; ++dt) o[dt][r] *= corr;
        }

        // P -> wave-private swizzled LDS (transpose to A-fragment layout)
        #pragma unroll
        for (int jt = 0; jt < 4; ++jt)
            #pragma unroll
            for (int r = 0; r < 4; ++r) {
                const int prow = 4 * lg + r, pcol = ln15 + 16 * jt;
                *reinterpret_cast<unsigned short*>(
                    pb + prow * 128 + ((pcol * 2) ^ ((prow & 7) << 4))) = f2bf(s[jt][r]);
            }
        const bfrag ap0 = *reinterpret_cast<const bfrag*>(
            pb + ln15 * 128 + ((lg * 16) ^ ((ln15 & 7) << 4)));
        const bfrag ap1 = *reinterpret_cast<const bfrag*>(
            pb + ln15 * 128 + ((64 + lg * 16) ^ ((ln15 & 7) << 4)));

        // O += P V
        __builtin_amdgcn_s_setprio(1);
        #pragma unroll
        for (int dt = 0; dt < 4; ++dt) {
            const int vrow = dt * 16 + ln15;
            const int sw = (vrow & 7) << 4;
            const bfrag v0 = *reinterpret_cast<const bfrag*>(vbh + vrow * 128 + ((lg * 16) ^ sw));
            const bfrag v1 = *reinterpret_cast<const bfrag*>(vbh + vrow * 128 + ((64 + lg * 16) ^ sw));
            o[dt] = MFMA16(ap0, v0, o[dt]);
            o[dt] = MFMA16(ap1, v1, o[dt]);
        }
        __builtin_amdgcn_s_setprio(0);

        __syncthreads();   // all waves done reading this tile
        WRITET();          // compiler inserts vmcnt wait; next tile -> LDS
        __syncthreads();   // staging visible
    }

    // write unnormalized partials
    const int q = blockIdx.y;
    #pragma unroll
    for (int dt = 0; dt < 4; ++dt)
        #pragma unroll
        for (int r = 0; r < 4; ++r) {
            const int grow = qrow0 + 4 * lg + r;
            po[((size_t)q * (NB * TSEQ) + grow) * HD + dt * 16 + ln15] = o[dt][r];
        }
    if (ln15 == 0) {
        #pragma unroll
        for (int r = 0; r < 4; ++r) {
            const int grow = qrow0 + 4 * lg + r;
            pm[q * (NB * TSEQ) + grow] = m[r];
            pl[q * (NB * TSEQ) + grow] = l[r];
        }
    }
}

// ---------------------------------------------------------------------------
// Merge NQ partials: out = sum_q po[q]*exp2(pm[q]-mx) / sum_q pl[q]*exp2(...)
// Thread = one (row, d) element; 64 consecutive threads share a row.
// ---------------------------------------------------------------------------
__global__ __launch_bounds__(256) void merge_kernel(
    const float* __restrict__ po, const float* __restrict__ pm,
    const float* __restrict__ pl, float* __restrict__ out)
{
    const int t   = blockIdx.x * 256 + threadIdx.x;
    const int row = t >> 6, d = t & 63;
    float mv[NQ];
    float mx = -__builtin_inff();
    #pragma unroll
    for (int q = 0; q < NQ; ++q) {
        mv[q] = pm[q * (NB * TSEQ) + row];
        mx = fmaxf(mx, mv[q]);
    }
    float lt = 0.f, acc = 0.f;
    #pragma unroll
    for (int q = 0; q < NQ; ++q) {
        const float wq = exp2f(mv[q] - mx);
        lt  += pl[q * (NB * TSEQ) + row] * wq;
        acc += po[((size_t)q * (NB * TSEQ) + row) * HD + d] * wq;
    }
    out[(size_t)row * HD + d] = acc / lt;
}

// ---------------------------------------------------------------------------
extern "C" void kernel_launch(void* const* d_in, const int* in_sizes, int n_in,
                              void* d_out, int out_size, void* d_ws, size_t ws_size,
                              hipStream_t stream) {
    (void)in_sizes; (void)n_in; (void)out_size; (void)ws_size;
    const float* x  = (const float*)d_in[0];
    const float* Wk = (const float*)d_in[1];
    const float* Wq = (const float*)d_in[2];
    const float* Wv = (const float*)d_in[3];

    const size_t NTOK = (size_t)NB * TSEQ;                 // 16384
    unsigned short* qb = (unsigned short*)d_ws;            // [16384][64] bf16
    unsigned short* kb = qb + NTOK * HD;                   // [16384][64] bf16
    unsigned short* vt = kb + NTOK * HD;                   // [4][64][4096] bf16
    unsigned short* wb = vt + NTOK * HD;                   // [192][1024] bf16
    float* po = (float*)(wb + 192 * CEMB);                 // [NQ][16384][64] f32
    float* pm = po + (size_t)NQ * NTOK * HD;               // [NQ][16384]
    float* pl = pm + (size_t)NQ * NTOK;                    // [NQ][16384]

    wcvt_kernel<<<192, 256, 0, stream>>>(Wq, Wk, Wv, wb);
    proj_kernel<<<512, 256, 0, stream>>>(x, wb, qb, kb, vt);
    attn_kernel<<<dim3(256, NQ), 256, 0, stream>>>(qb, kb, vt, po, pm, pl);
    merge_kernel<<<4096, 256, 0, stream>>>(po, pm, pl, (float*)d_out);
}

// Round 4
// 117.708 us; speedup vs baseline: 1.7818x; 1.2043x over previous
//
#include <hip/hip_runtime.h>
#include <hip/hip_bf16.h>
#include <cstdint>

#define TSEQ 4096
#define NB   4
#define HD   64
#define CEMB 1024
#define NQ   4                 // KV quarters (attention parallelism)
#define NTOK (NB * TSEQ)       // 16384
#define SCL  0.18033688011112042f   // 0.125 * log2(e), folded into q at proj

typedef __attribute__((ext_vector_type(8)))  short bfrag;   // 8 bf16 = 4 VGPRs
typedef __attribute__((ext_vector_type(4)))  float f4;
typedef __attribute__((ext_vector_type(16))) float f16v;

#define MFMA16(a, b, c) __builtin_amdgcn_mfma_f32_16x16x32_bf16(a, b, c, 0, 0, 0)
#define MFMA32(a, b, c) __builtin_amdgcn_mfma_f32_32x32x16_bf16(a, b, c, 0, 0, 0)

static __device__ __forceinline__ unsigned short f2bf(float f) {
    __hip_bfloat16 h = __float2bfloat16(f);
    return __builtin_bit_cast(unsigned short, h);
}

static __device__ __forceinline__ unsigned cvtpk(float lo, float hi) {
    unsigned r;
    asm("v_cvt_pk_bf16_f32 %0, %1, %2" : "=v"(r) : "v"(lo), "v"(hi));
    return r;
}

static __device__ __forceinline__ bfrag cvt8(const float* p) {
    const float4 a = *reinterpret_cast<const float4*>(p);
    const float4 b = *reinterpret_cast<const float4*>(p + 4);
    bfrag r;
    r[0] = (short)f2bf(a.x); r[1] = (short)f2bf(a.y);
    r[2] = (short)f2bf(a.z); r[3] = (short)f2bf(a.w);
    r[4] = (short)f2bf(b.x); r[5] = (short)f2bf(b.y);
    r[6] = (short)f2bf(b.z); r[7] = (short)f2bf(b.w);
    return r;
}

// ---------------------------------------------------------------------------
// x (f32 [16384][1024]) -> xb (bf16), pure streaming.
// ---------------------------------------------------------------------------
__global__ __launch_bounds__(256) void xcvt_kernel(
    const float* __restrict__ x, unsigned short* __restrict__ xb)
{
    size_t base = ((size_t)blockIdx.x * 256 + threadIdx.x) * 8;
    const size_t stride = (size_t)2048 * 256 * 8;
    #pragma unroll
    for (int r = 0; r < 4; ++r, base += stride)
        *reinterpret_cast<bfrag*>(xb + base) = cvt8(x + base);
}

// ---------------------------------------------------------------------------
// W conversion: Wq|Wk|Wv (each [64][1024] f32) -> wb [192][1024] bf16, once.
// ---------------------------------------------------------------------------
__global__ __launch_bounds__(256) void wcvt_kernel(
    const float* __restrict__ Wq, const float* __restrict__ Wk,
    const float* __restrict__ Wv, unsigned short* __restrict__ wb)
{
    const int row = blockIdx.x;          // 0..191
    const int col = threadIdx.x * 4;     // 0..1020
    const float* W = (row < 64) ? Wq + (size_t)row * CEMB
                   : (row < 128) ? Wk + (size_t)(row - 64) * CEMB
                   : Wv + (size_t)(row - 128) * CEMB;
    const float4 v = *reinterpret_cast<const float4*>(W + col);
    ushort4 o;
    o.x = f2bf(v.x); o.y = f2bf(v.y); o.z = f2bf(v.z); o.w = f2bf(v.w);
    *reinterpret_cast<ushort4*>(wb + (size_t)row * CEMB + col) = o;
}

// ---------------------------------------------------------------------------
// Projection (pure bf16 GEMM): wave = 16 rows x 96 cols. Block = 4 waves.
// Grid 512 -> 2 blocks/CU. q columns pre-scaled by SCL.
// ---------------------------------------------------------------------------
__global__ __launch_bounds__(256) void proj_kernel(
    const unsigned short* __restrict__ xb, const unsigned short* __restrict__ wb,
    unsigned short* __restrict__ qb, unsigned short* __restrict__ kb,
    unsigned short* __restrict__ vt)
{
    const int w    = threadIdx.x >> 6;
    const int lane = threadIdx.x & 63;
    const int ln15 = lane & 15, lg = lane >> 4;
    const int row0  = blockIdx.x * 32 + (w >> 1) * 16;
    const int cbase = (w & 1) * 96;

    f4 acc[6];
    #pragma unroll
    for (int j = 0; j < 6; ++j) acc[j] = f4{0.f, 0.f, 0.f, 0.f};

    const unsigned short* xrow = xb + (size_t)(row0 + ln15) * CEMB + 8 * lg;
    const unsigned short* wrow = wb + (size_t)(cbase + ln15) * CEMB + 8 * lg;

    #pragma unroll 4
    for (int k0 = 0; k0 < CEMB; k0 += 32) {
        const bfrag a = *reinterpret_cast<const bfrag*>(xrow + k0);
        #pragma unroll
        for (int ct = 0; ct < 6; ++ct) {
            const bfrag bw = *reinterpret_cast<const bfrag*>(wrow + ct * 16 * CEMB + k0);
            acc[ct] = MFMA16(a, bw, acc[ct]);
        }
    }

    // D layout: col = lane&15, row = 4*(lane>>4) + reg
    #pragma unroll
    for (int ct = 0; ct < 6; ++ct) {
        const int c = cbase + ct * 16 + ln15;
        #pragma unroll
        for (int r = 0; r < 4; ++r) {
            const int grow = row0 + 4 * lg + r;
            if (c < 64)        qb[(size_t)grow * HD + c] = f2bf(acc[ct][r] * SCL);
            else if (c < 128)  kb[(size_t)grow * HD + (c - 64)] = f2bf(acc[ct][r]);
            else {
                const int bbi = grow >> 12, t = grow & 4095;
                vt[((size_t)(bbi * HD + (c - 128)) << 12) + t] = f2bf(acc[ct][r]);
            }
        }
    }
}

// ---------------------------------------------------------------------------
// Flash attention partials, 32x32 swapped-operand structure.
// Grid (128, NQ): blockIdx.x = 128-q-row group, blockIdx.y = KV quarter.
// Block = 4 waves, wave = 32 q rows. S^T = mfma32(K, Q): lane owns one
// q-column (q = lane&31); softmax = in-register tree + shfl_xor(32).
// P repacked in-register via cvt_pk + permlane32_swap. O^T = mfma32(V^T, P^T).
// Double-buffered LDS, one barrier/iter, T14 early loads, T5 setprio.
// ---------------------------------------------------------------------------
__global__ __launch_bounds__(256, 2) void attn_kernel(
    const unsigned short* __restrict__ qb, const unsigned short* __restrict__ kb,
    const unsigned short* __restrict__ vt, float* __restrict__ po,
    float* __restrict__ pm, float* __restrict__ pl)
{
    __shared__ __attribute__((aligned(16))) unsigned short kbuf[2][64 * 64];
    __shared__ __attribute__((aligned(16))) unsigned short vbuf[2][64 * 64];

    const int w    = threadIdx.x >> 6;
    const int lane = threadIdx.x & 63;
    const int ql   = lane & 31;          // this lane's q (column) index
    const int hi   = lane >> 5;
    const int q0   = blockIdx.x * 128 + w * 32;
    const int bb   = blockIdx.x >> 5;    // batch index
    const int kvbase = blockIdx.y * 1024;

    const size_t kgbase = (size_t)bb * TSEQ * HD;
    const size_t vgbase = (size_t)bb * HD * TSEQ;

    // Q fragments (B-operand): col = ql, k-chunk s: c = 16s + 8*hi + j
    bfrag aq[4];
    #pragma unroll
    for (int s = 0; s < 4; ++s)
        aq[s] = *reinterpret_cast<const bfrag*>(
            qb + (size_t)(q0 + ql) * HD + 16 * s + 8 * hi);

    f16v o0, o1;
    #pragma unroll
    for (int i = 0; i < 16; ++i) { o0[i] = 0.f; o1[i] = 0.f; }
    float m = -__builtin_inff(), lsum = 0.f;

    // staging: 256 thr, K tile 512 segs + V tile 512 segs -> 4 segs/thread
    const int rr  = threadIdx.x >> 3;    // 0..31
    const int rr2 = rr + 32;
    const int seg = threadIdx.x & 7;
    const int dstA = rr  * 128 + ((seg * 16) ^ ((rr  & 7) << 4));
    const int dstB = rr2 * 128 + ((seg * 16) ^ ((rr2 & 7) << 4));

    bfrag st0, st1, st2, st3;
    auto LOADT = [&](int kv0) {
        st0 = *reinterpret_cast<const bfrag*>(kb + kgbase + (size_t)(kv0 + rr)  * HD + seg * 8);
        st1 = *reinterpret_cast<const bfrag*>(kb + kgbase + (size_t)(kv0 + rr2) * HD + seg * 8);
        st2 = *reinterpret_cast<const bfrag*>(vt + vgbase + (size_t)rr  * TSEQ + kv0 + seg * 8);
        st3 = *reinterpret_cast<const bfrag*>(vt + vgbase + (size_t)rr2 * TSEQ + kv0 + seg * 8);
    };
    auto WRITET = [&](int c) {
        char* kd = (char*)kbuf[c];
        char* vd = (char*)vbuf[c];
        *reinterpret_cast<bfrag*>(kd + dstA) = st0;
        *reinterpret_cast<bfrag*>(kd + dstB) = st1;
        *reinterpret_cast<bfrag*>(vd + dstA) = st2;
        *reinterpret_cast<bfrag*>(vd + dstB) = st3;
    };

    // repack P^T tile -> B-fragment for kv chunk (T12). Group u0 = regs
    // 4u0..4u0+3, group u0+1 = 4u0+4..7; permlane32_swap exchanges halves.
    auto mkpa = [&](const f16v& p, const int u0) -> bfrag {
        unsigned a0 = cvtpk(p[4 * u0 + 0], p[4 * u0 + 1]);
        unsigned a1 = cvtpk(p[4 * u0 + 2], p[4 * u0 + 3]);
        unsigned b0 = cvtpk(p[4 * u0 + 4], p[4 * u0 + 5]);
        unsigned b1 = cvtpk(p[4 * u0 + 6], p[4 * u0 + 7]);
        asm("v_permlane32_swap_b32 %0, %1" : "+v"(a0), "+v"(b0));
        asm("v_permlane32_swap_b32 %0, %1" : "+v"(a1), "+v"(b1));
        const uint4 u = make_uint4(a0, a1, b0, b1);
        return __builtin_bit_cast(bfrag, u);
    };

    LOADT(kvbase);
    WRITET(0);
    __syncthreads();

    const int swz = (ql & 7) << 4;

    for (int it = 0; it < 16; ++it) {
        const int c = it & 1;
        if (it < 15) LOADT(kvbase + (it + 1) * 64);   // T14: issue early

        const char* kbh = (const char*)kbuf[c];
        const char* vbh = (const char*)vbuf[c];

        // S^T = K . Q^T : tiles (kv 0-31, 32-63), 4 chunks of k=16
        f16v s0v, s1v;
        #pragma unroll
        for (int i = 0; i < 16; ++i) { s0v[i] = 0.f; s1v[i] = 0.f; }
        __builtin_amdgcn_s_setprio(1);
        #pragma unroll
        for (int s = 0; s < 4; ++s) {
            const int off = (32 * s + 16 * hi) ^ swz;
            const bfrag k0 = *reinterpret_cast<const bfrag*>(kbh + ql * 128 + off);
            const bfrag k1 = *reinterpret_cast<const bfrag*>(kbh + (ql + 32) * 128 + off);
            s0v = MFMA32(k0, aq[s], s0v);
            s1v = MFMA32(k1, aq[s], s1v);
        }
        __builtin_amdgcn_s_setprio(0);

        // ---- online softmax, lane-local (q = ql) ----
        float b[16];
        #pragma unroll
        for (int i = 0; i < 16; ++i) b[i] = fmaxf(s0v[i], s1v[i]);
        #pragma unroll
        for (int st = 8; st > 0; st >>= 1)
            #pragma unroll
            for (int i = 0; i < 8; ++i) if (i < st) b[i] = fmaxf(b[i], b[i + st]);
        float tmax = b[0];
        tmax = fmaxf(tmax, __shfl_xor(tmax, 32));
        const float mn   = fmaxf(m, tmax);
        const float corr = exp2f(m - mn);
        m = mn;
        #pragma unroll
        for (int i = 0; i < 16; ++i) {
            s0v[i] = exp2f(s0v[i] - mn);
            s1v[i] = exp2f(s1v[i] - mn);
        }
        float a[16];
        #pragma unroll
        for (int i = 0; i < 16; ++i) a[i] = s0v[i] + s1v[i];
        #pragma unroll
        for (int st = 8; st > 0; st >>= 1)
            #pragma unroll
            for (int i = 0; i < 8; ++i) if (i < st) a[i] += a[i + st];
        float sum = a[0];
        sum += __shfl_xor(sum, 32);
        lsum = lsum * corr + sum;
        #pragma unroll
        for (int i = 0; i < 16; ++i) { o0[i] *= corr; o1[i] *= corr; }

        // ---- repack P to B-fragments (in-register) ----
        const bfrag pa0 = mkpa(s0v, 0);
        const bfrag pa1 = mkpa(s0v, 2);
        const bfrag pa2 = mkpa(s1v, 0);
        const bfrag pa3 = mkpa(s1v, 2);

        // ---- O^T += V^T . P^T ----
        __builtin_amdgcn_s_setprio(1);
        #pragma unroll
        for (int s = 0; s < 4; ++s) {
            const int off = (32 * s + 16 * hi) ^ swz;
            const bfrag v0 = *reinterpret_cast<const bfrag*>(vbh + ql * 128 + off);
            const bfrag v1 = *reinterpret_cast<const bfrag*>(vbh + (ql + 32) * 128 + off);
            const bfrag pa = (s == 0) ? pa0 : (s == 1) ? pa1 : (s == 2) ? pa2 : pa3;
            o0 = MFMA32(v0, pa, o0);
            o1 = MFMA32(v1, pa, o1);
        }
        __builtin_amdgcn_s_setprio(0);

        if (it < 15) WRITET(c ^ 1);   // waits on LOADT's vmcnt internally
        __syncthreads();
    }

    // ---- partial write: lane holds q = ql, d = 32h + 8u + 4hi + r ----
    const size_t obase = ((size_t)blockIdx.y * NTOK + (q0 + ql)) * HD;
    #pragma unroll
    for (int u = 0; u < 4; ++u) {
        f4 w0 = { o0[4 * u], o0[4 * u + 1], o0[4 * u + 2], o0[4 * u + 3] };
        *reinterpret_cast<f4*>(po + obase + 8 * u + 4 * hi) = w0;
        f4 w1 = { o1[4 * u], o1[4 * u + 1], o1[4 * u + 2], o1[4 * u + 3] };
        *reinterpret_cast<f4*>(po + obase + 32 + 8 * u + 4 * hi) = w1;
    }
    if (hi == 0) {
        pm[blockIdx.y * NTOK + q0 + ql] = m;
        pl[blockIdx.y * NTOK + q0 + ql] = lsum;
    }
}

// ---------------------------------------------------------------------------
// Merge NQ partials.
// ---------------------------------------------------------------------------
__global__ __launch_bounds__(256) void merge_kernel(
    const float* __restrict__ po, const float* __restrict__ pm,
    const float* __restrict__ pl, float* __restrict__ out)
{
    const int t   = blockIdx.x * 256 + threadIdx.x;
    const int row = t >> 6, d = t & 63;
    float mv[NQ];
    float mx = -__builtin_inff();
    #pragma unroll
    for (int q = 0; q < NQ; ++q) {
        mv[q] = pm[q * NTOK + row];
        mx = fmaxf(mx, mv[q]);
    }
    float lt = 0.f, acc = 0.f;
    #pragma unroll
    for (int q = 0; q < NQ; ++q) {
        const float wq = exp2f(mv[q] - mx);
        lt  += pl[q * NTOK + row] * wq;
        acc += po[((size_t)q * NTOK + row) * HD + d] * wq;
    }
    out[(size_t)row * HD + d] = acc / lt;
}

// ---------------------------------------------------------------------------
extern "C" void kernel_launch(void* const* d_in, const int* in_sizes, int n_in,
                              void* d_out, int out_size, void* d_ws, size_t ws_size,
                              hipStream_t stream) {
    (void)in_sizes; (void)n_in; (void)out_size; (void)ws_size;
    const float* x  = (const float*)d_in[0];
    const float* Wk = (const float*)d_in[1];
    const float* Wq = (const float*)d_in[2];
    const float* Wv = (const float*)d_in[3];

    unsigned short* qb = (unsigned short*)d_ws;            // [16384][64] bf16
    unsigned short* kb = qb + (size_t)NTOK * HD;           // [16384][64] bf16
    unsigned short* vt = kb + (size_t)NTOK * HD;           // [4][64][4096] bf16
    unsigned short* wb = vt + (size_t)NTOK * HD;           // [192][1024] bf16
    unsigned short* xb = wb + (size_t)192 * CEMB;          // [16384][1024] bf16 (32 MB)
    // po/pm/pl alias xb: proj's last read of xb precedes attn's first write.
    float* po = (float*)xb;                                // [NQ][16384][64] f32
    float* pm = po + (size_t)NQ * NTOK * HD;               // [NQ][16384]
    float* pl = pm + (size_t)NQ * NTOK;                    // [NQ][16384]

    xcvt_kernel<<<2048, 256, 0, stream>>>(x, xb);
    wcvt_kernel<<<192, 256, 0, stream>>>(Wq, Wk, Wv, wb);
    proj_kernel<<<512, 256, 0, stream>>>(xb, wb, qb, kb, vt);
    attn_kernel<<<dim3(128, NQ), 256, 0, stream>>>(qb, kb, vt, po, pm, pl);
    merge_kernel<<<4096, 256, 0, stream>>>(po, pm, pl, (float*)d_out);
}

// Round 5
// 71.921 us; speedup vs baseline: 2.9161x; 1.6366x over previous
//
#include <hip/hip_runtime.h>
#include <hip/hip_bf16.h>
#include <cstdint>

#define TSEQ 4096
#define NB   4
#define HD   64
#define CEMB 1024
#define NQ   4                 // KV quarters (attention parallelism)
#define NTOK (NB * TSEQ)       // 16384
#define SCL  0.18033688011112042f   // 0.125 * log2(e), folded into q at proj

typedef __attribute__((ext_vector_type(8)))  short bfrag;   // 8 bf16 = 4 VGPRs
typedef __attribute__((ext_vector_type(4)))  float f4;
typedef __attribute__((ext_vector_type(16))) float f16v;

#define MFMA16(a, b, c) __builtin_amdgcn_mfma_f32_16x16x32_bf16(a, b, c, 0, 0, 0)
#define MFMA32(a, b, c) __builtin_amdgcn_mfma_f32_32x32x16_bf16(a, b, c, 0, 0, 0)

static __device__ __forceinline__ unsigned short f2bf(float f) {
    __hip_bfloat16 h = __float2bfloat16(f);
    return __builtin_bit_cast(unsigned short, h);
}

static __device__ __forceinline__ unsigned cvtpk(float lo, float hi) {
    unsigned r;
    asm("v_cvt_pk_bf16_f32 %0, %1, %2" : "=v"(r) : "v"(lo), "v"(hi));
    return r;
}

// ---------------------------------------------------------------------------
// W conversion: Wq|Wk|Wv (each [64][1024] f32) -> wb [192][1024] bf16, once.
// ---------------------------------------------------------------------------
__global__ __launch_bounds__(256) void wcvt_kernel(
    const float* __restrict__ Wq, const float* __restrict__ Wk,
    const float* __restrict__ Wv, unsigned short* __restrict__ wb)
{
    const int row = blockIdx.x;          // 0..191
    const int col = threadIdx.x * 4;     // 0..1020
    const float* W = (row < 64) ? Wq + (size_t)row * CEMB
                   : (row < 128) ? Wk + (size_t)(row - 64) * CEMB
                   : Wv + (size_t)(row - 128) * CEMB;
    const float4 v = *reinterpret_cast<const float4*>(W + col);
    ushort4 o;
    o.x = f2bf(v.x); o.y = f2bf(v.y); o.z = f2bf(v.z); o.w = f2bf(v.w);
    *reinterpret_cast<ushort4*>(wb + (size_t)row * CEMB + col) = o;
}

// ---------------------------------------------------------------------------
// Projection, LDS-staged GEMM with fused f32->bf16 conversion of x.
// Grid 256: block = 64 rows x 192 cols, 4 waves (2 rowg x 2 colg),
// wave = 32 rows x 96 cols (acc 2x6 f4). K-chunks of 64, double-buffered
// XOR-swizzled LDS; T14: load chunk k+1 to regs, compute chunk k, write LDS,
// one barrier per chunk. q columns pre-scaled by SCL.
// ---------------------------------------------------------------------------
__global__ __launch_bounds__(256) void proj_kernel(
    const float* __restrict__ x, const unsigned short* __restrict__ wb,
    unsigned short* __restrict__ qb, unsigned short* __restrict__ kb,
    unsigned short* __restrict__ vt)
{
    __shared__ __attribute__((aligned(16))) unsigned short xs[2][64 * 64];
    __shared__ __attribute__((aligned(16))) unsigned short ws[2][192 * 64];

    const int tid  = threadIdx.x;
    const int w    = tid >> 6;
    const int lane = tid & 63;
    const int ln15 = lane & 15, lg = lane >> 4;
    const int rowg = (w >> 1) * 32;          // 0 / 32 within block
    const int colg = (w & 1) * 96;           // 0 / 96
    const int rowbase = blockIdx.x * 64;

    f4 acc[2][6];
    #pragma unroll
    for (int i = 0; i < 2; ++i)
        #pragma unroll
        for (int j = 0; j < 6; ++j) acc[i][j] = f4{0.f, 0.f, 0.f, 0.f};

    // staging geometry
    const int xrow = tid >> 2;               // 0..63
    const int xs16 = tid & 3;                // 16-f32 column group
    const int xswz = (xrow & 7) << 4;

    float4 xf[4];
    bfrag  wf[6];
    auto LOADP = [&](int k0) {
        const float* xsrc = x + (size_t)(rowbase + xrow) * CEMB + k0 + xs16 * 16;
        #pragma unroll
        for (int i = 0; i < 4; ++i)
            xf[i] = reinterpret_cast<const float4*>(xsrc)[i];
        #pragma unroll
        for (int i = 0; i < 6; ++i) {
            const int seg = tid + i * 256;           // 0..1535
            const int srow = seg >> 3, sc = seg & 7;
            wf[i] = *reinterpret_cast<const bfrag*>(wb + (size_t)srow * CEMB + k0 + sc * 8);
        }
    };
    auto WRITEP = [&](int c) {
        char* xd = (char*)xs[c];
        char* wd = (char*)ws[c];
        uint4 lo, hi;
        lo.x = cvtpk(xf[0].x, xf[0].y); lo.y = cvtpk(xf[0].z, xf[0].w);
        lo.z = cvtpk(xf[1].x, xf[1].y); lo.w = cvtpk(xf[1].z, xf[1].w);
        hi.x = cvtpk(xf[2].x, xf[2].y); hi.y = cvtpk(xf[2].z, xf[2].w);
        hi.z = cvtpk(xf[3].x, xf[3].y); hi.w = cvtpk(xf[3].z, xf[3].w);
        *reinterpret_cast<uint4*>(xd + xrow * 128 + ((xs16 * 32) ^ xswz)) = lo;
        *reinterpret_cast<uint4*>(xd + xrow * 128 + ((xs16 * 32 + 16) ^ xswz)) = hi;
        #pragma unroll
        for (int i = 0; i < 6; ++i) {
            const int seg = tid + i * 256;
            const int srow = seg >> 3, sc = seg & 7;
            *reinterpret_cast<bfrag*>(wd + srow * 128 + ((sc * 16) ^ ((srow & 7) << 4))) = wf[i];
        }
    };

    LOADP(0);
    WRITEP(0);
    __syncthreads();

    for (int ch = 0; ch < 16; ++ch) {
        const int c = ch & 1;
        if (ch < 15) LOADP((ch + 1) * 64);   // T14: issue early

        const char* xp = (const char*)xs[c];
        const char* wp = (const char*)ws[c];
        __builtin_amdgcn_s_setprio(1);
        #pragma unroll
        for (int ks = 0; ks < 2; ++ks) {
            const int cb = ks * 64 + lg * 16;
            const int r0 = rowg + ln15, r1 = rowg + 16 + ln15;
            const bfrag a0 = *reinterpret_cast<const bfrag*>(xp + r0 * 128 + (cb ^ ((r0 & 7) << 4)));
            const bfrag a1 = *reinterpret_cast<const bfrag*>(xp + r1 * 128 + (cb ^ ((r1 & 7) << 4)));
            #pragma unroll
            for (int ct = 0; ct < 6; ++ct) {
                const int wr = colg + ct * 16 + ln15;
                const bfrag b = *reinterpret_cast<const bfrag*>(wp + wr * 128 + (cb ^ ((wr & 7) << 4)));
                acc[0][ct] = MFMA16(a0, b, acc[0][ct]);
                acc[1][ct] = MFMA16(a1, b, acc[1][ct]);
            }
        }
        __builtin_amdgcn_s_setprio(0);

        if (ch < 15) WRITEP(c ^ 1);   // prev readers of c^1 done before last barrier
        __syncthreads();
    }

    // D layout: col = lane&15, row = 4*(lane>>4) + reg
    #pragma unroll
    for (int rt = 0; rt < 2; ++rt) {
        #pragma unroll
        for (int ct = 0; ct < 6; ++ct) {
            const int c = colg + ct * 16 + ln15;
            #pragma unroll
            for (int r = 0; r < 4; ++r) {
                const int grow = rowbase + rowg + rt * 16 + 4 * lg + r;
                if (c < 64)        qb[(size_t)grow * HD + c] = f2bf(acc[rt][ct][r] * SCL);
                else if (c < 128)  kb[(size_t)grow * HD + (c - 64)] = f2bf(acc[rt][ct][r]);
                else {
                    const int bbi = grow >> 12, t = grow & 4095;
                    vt[((size_t)(bbi * HD + (c - 128)) << 12) + t] = f2bf(acc[rt][ct][r]);
                }
            }
        }
    }
}

// ---------------------------------------------------------------------------
// Flash attention partials, 32x32 swapped-operand structure (unchanged).
// ---------------------------------------------------------------------------
__global__ __launch_bounds__(256, 2) void attn_kernel(
    const unsigned short* __restrict__ qb, const unsigned short* __restrict__ kb,
    const unsigned short* __restrict__ vt, float* __restrict__ po,
    float* __restrict__ pm, float* __restrict__ pl)
{
    __shared__ __attribute__((aligned(16))) unsigned short kbuf[2][64 * 64];
    __shared__ __attribute__((aligned(16))) unsigned short vbuf[2][64 * 64];

    const int w    = threadIdx.x >> 6;
    const int lane = threadIdx.x & 63;
    const int ql   = lane & 31;          // this lane's q (column) index
    const int hi   = lane >> 5;
    const int q0   = blockIdx.x * 128 + w * 32;
    const int bb   = blockIdx.x >> 5;    // batch index
    const int kvbase = blockIdx.y * 1024;

    const size_t kgbase = (size_t)bb * TSEQ * HD;
    const size_t vgbase = (size_t)bb * HD * TSEQ;

    bfrag aq[4];
    #pragma unroll
    for (int s = 0; s < 4; ++s)
        aq[s] = *reinterpret_cast<const bfrag*>(
            qb + (size_t)(q0 + ql) * HD + 16 * s + 8 * hi);

    f16v o0, o1;
    #pragma unroll
    for (int i = 0; i < 16; ++i) { o0[i] = 0.f; o1[i] = 0.f; }
    float m = -__builtin_inff(), lsum = 0.f;

    const int rr  = threadIdx.x >> 3;    // 0..31
    const int rr2 = rr + 32;
    const int seg = threadIdx.x & 7;
    const int dstA = rr  * 128 + ((seg * 16) ^ ((rr  & 7) << 4));
    const int dstB = rr2 * 128 + ((seg * 16) ^ ((rr2 & 7) << 4));

    bfrag st0, st1, st2, st3;
    auto LOADT = [&](int kv0) {
        st0 = *reinterpret_cast<const bfrag*>(kb + kgbase + (size_t)(kv0 + rr)  * HD + seg * 8);
        st1 = *reinterpret_cast<const bfrag*>(kb + kgbase + (size_t)(kv0 + rr2) * HD + seg * 8);
        st2 = *reinterpret_cast<const bfrag*>(vt + vgbase + (size_t)rr  * TSEQ + kv0 + seg * 8);
        st3 = *reinterpret_cast<const bfrag*>(vt + vgbase + (size_t)rr2 * TSEQ + kv0 + seg * 8);
    };
    auto WRITET = [&](int c) {
        char* kd = (char*)kbuf[c];
        char* vd = (char*)vbuf[c];
        *reinterpret_cast<bfrag*>(kd + dstA) = st0;
        *reinterpret_cast<bfrag*>(kd + dstB) = st1;
        *reinterpret_cast<bfrag*>(vd + dstA) = st2;
        *reinterpret_cast<bfrag*>(vd + dstB) = st3;
    };

    auto mkpa = [&](const f16v& p, const int u0) -> bfrag {
        unsigned a0 = cvtpk(p[4 * u0 + 0], p[4 * u0 + 1]);
        unsigned a1 = cvtpk(p[4 * u0 + 2], p[4 * u0 + 3]);
        unsigned b0 = cvtpk(p[4 * u0 + 4], p[4 * u0 + 5]);
        unsigned b1 = cvtpk(p[4 * u0 + 6], p[4 * u0 + 7]);
        asm("v_permlane32_swap_b32 %0, %1" : "+v"(a0), "+v"(b0));
        asm("v_permlane32_swap_b32 %0, %1" : "+v"(a1), "+v"(b1));
        const uint4 u = make_uint4(a0, a1, b0, b1);
        return __builtin_bit_cast(bfrag, u);
    };

    LOADT(kvbase);
    WRITET(0);
    __syncthreads();

    const int swz = (ql & 7) << 4;

    for (int it = 0; it < 16; ++it) {
        const int c = it & 1;
        if (it < 15) LOADT(kvbase + (it + 1) * 64);   // T14: issue early

        const char* kbh = (const char*)kbuf[c];
        const char* vbh = (const char*)vbuf[c];

        f16v s0v, s1v;
        #pragma unroll
        for (int i = 0; i < 16; ++i) { s0v[i] = 0.f; s1v[i] = 0.f; }
        __builtin_amdgcn_s_setprio(1);
        #pragma unroll
        for (int s = 0; s < 4; ++s) {
            const int off = (32 * s + 16 * hi) ^ swz;
            const bfrag k0 = *reinterpret_cast<const bfrag*>(kbh + ql * 128 + off);
            const bfrag k1 = *reinterpret_cast<const bfrag*>(kbh + (ql + 32) * 128 + off);
            s0v = MFMA32(k0, aq[s], s0v);
            s1v = MFMA32(k1, aq[s], s1v);
        }
        __builtin_amdgcn_s_setprio(0);

        // ---- online softmax, lane-local (q = ql) ----
        float b[16];
        #pragma unroll
        for (int i = 0; i < 16; ++i) b[i] = fmaxf(s0v[i], s1v[i]);
        #pragma unroll
        for (int st = 8; st > 0; st >>= 1)
            #pragma unroll
            for (int i = 0; i < 8; ++i) if (i < st) b[i] = fmaxf(b[i], b[i + st]);
        float tmax = b[0];
        tmax = fmaxf(tmax, __shfl_xor(tmax, 32));
        const float mn   = fmaxf(m, tmax);
        const float corr = exp2f(m - mn);
        m = mn;
        #pragma unroll
        for (int i = 0; i < 16; ++i) {
            s0v[i] = exp2f(s0v[i] - mn);
            s1v[i] = exp2f(s1v[i] - mn);
        }
        float a[16];
        #pragma unroll
        for (int i = 0; i < 16; ++i) a[i] = s0v[i] + s1v[i];
        #pragma unroll
        for (int st = 8; st > 0; st >>= 1)
            #pragma unroll
            for (int i = 0; i < 8; ++i) if (i < st) a[i] += a[i + st];
        float sum = a[0];
        sum += __shfl_xor(sum, 32);
        lsum = lsum * corr + sum;
        #pragma unroll
        for (int i = 0; i < 16; ++i) { o0[i] *= corr; o1[i] *= corr; }

        const bfrag pa0 = mkpa(s0v, 0);
        const bfrag pa1 = mkpa(s0v, 2);
        const bfrag pa2 = mkpa(s1v, 0);
        const bfrag pa3 = mkpa(s1v, 2);

        __builtin_amdgcn_s_setprio(1);
        #pragma unroll
        for (int s = 0; s < 4; ++s) {
            const int off = (32 * s + 16 * hi) ^ swz;
            const bfrag v0 = *reinterpret_cast<const bfrag*>(vbh + ql * 128 + off);
            const bfrag v1 = *reinterpret_cast<const bfrag*>(vbh + (ql + 32) * 128 + off);
            const bfrag pa = (s == 0) ? pa0 : (s == 1) ? pa1 : (s == 2) ? pa2 : pa3;
            o0 = MFMA32(v0, pa, o0);
            o1 = MFMA32(v1, pa, o1);
        }
        __builtin_amdgcn_s_setprio(0);

        if (it < 15) WRITET(c ^ 1);
        __syncthreads();
    }

    const size_t obase = ((size_t)blockIdx.y * NTOK + (q0 + ql)) * HD;
    #pragma unroll
    for (int u = 0; u < 4; ++u) {
        f4 w0 = { o0[4 * u], o0[4 * u + 1], o0[4 * u + 2], o0[4 * u + 3] };
        *reinterpret_cast<f4*>(po + obase + 8 * u + 4 * hi) = w0;
        f4 w1 = { o1[4 * u], o1[4 * u + 1], o1[4 * u + 2], o1[4 * u + 3] };
        *reinterpret_cast<f4*>(po + obase + 32 + 8 * u + 4 * hi) = w1;
    }
    if (hi == 0) {
        pm[blockIdx.y * NTOK + q0 + ql] = m;
        pl[blockIdx.y * NTOK + q0 + ql] = lsum;
    }
}

// ---------------------------------------------------------------------------
// Merge NQ partials.
// ---------------------------------------------------------------------------
__global__ __launch_bounds__(256) void merge_kernel(
    const float* __restrict__ po, const float* __restrict__ pm,
    const float* __restrict__ pl, float* __restrict__ out)
{
    const int t   = blockIdx.x * 256 + threadIdx.x;
    const int row = t >> 6, d = t & 63;
    float mv[NQ];
    float mx = -__builtin_inff();
    #pragma unroll
    for (int q = 0; q < NQ; ++q) {
        mv[q] = pm[q * NTOK + row];
        mx = fmaxf(mx, mv[q]);
    }
    float lt = 0.f, acc = 0.f;
    #pragma unroll
    for (int q = 0; q < NQ; ++q) {
        const float wq = exp2f(mv[q] - mx);
        lt  += pl[q * NTOK + row] * wq;
        acc += po[((size_t)q * NTOK + row) * HD + d] * wq;
    }
    out[(size_t)row * HD + d] = acc / lt;
}

// ---------------------------------------------------------------------------
extern "C" void kernel_launch(void* const* d_in, const int* in_sizes, int n_in,
                              void* d_out, int out_size, void* d_ws, size_t ws_size,
                              hipStream_t stream) {
    (void)in_sizes; (void)n_in; (void)out_size; (void)ws_size;
    const float* x  = (const float*)d_in[0];
    const float* Wk = (const float*)d_in[1];
    const float* Wq = (const float*)d_in[2];
    const float* Wv = (const float*)d_in[3];

    unsigned short* qb = (unsigned short*)d_ws;            // [16384][64] bf16
    unsigned short* kb = qb + (size_t)NTOK * HD;           // [16384][64] bf16
    unsigned short* vt = kb + (size_t)NTOK * HD;           // [4][64][4096] bf16
    unsigned short* wb = vt + (size_t)NTOK * HD;           // [192][1024] bf16
    float* po = (float*)(wb + (size_t)192 * CEMB);         // [NQ][16384][64] f32
    float* pm = po + (size_t)NQ * NTOK * HD;               // [NQ][16384]
    float* pl = pm + (size_t)NQ * NTOK;                    // [NQ][16384]

    wcvt_kernel<<<192, 256, 0, stream>>>(Wq, Wk, Wv, wb);
    proj_kernel<<<256, 256, 0, stream>>>(x, wb, qb, kb, vt);
    attn_kernel<<<dim3(128, NQ), 256, 0, stream>>>(qb, kb, vt, po, pm, pl);
    merge_kernel<<<4096, 256, 0, stream>>>(po, pm, pl, (float*)d_out);
}